// Round 1
// baseline (2505.296 us; speedup 1.0000x reference)
//
#include <hip/hip_runtime.h>

#define N_NODES 200000
#define N_EDGES 6400000
#define HID 128
#define OUTF 16
#define LAYERS 3
#define EPS 1e-5f

typedef unsigned int u32;

__device__ __forceinline__ unsigned short f2bf(float f){
  unsigned int u = __float_as_uint(f);
  u += 0x7fffu + ((u >> 16) & 1u);   // RNE
  return (unsigned short)(u >> 16);
}

// ---------------- CSR build ----------------

__global__ __launch_bounds__(256) void k_deg(const int* __restrict__ dst, int* __restrict__ cnt){
  int e = blockIdx.x * 256 + threadIdx.x;      // grid covers E exactly
  atomicAdd(&cnt[dst[e]], 1);
}

// per-block exclusive scan of 1024 elems (256 thr x 4)
__global__ __launch_bounds__(256) void k_scan1(const int* __restrict__ in, int* __restrict__ out,
                                               int* __restrict__ bsum, int n){
  __shared__ int s[256];
  int tid = threadIdx.x;
  int base = blockIdx.x * 1024 + tid * 4;
  int v[4]; int tsum = 0;
  #pragma unroll
  for (int i = 0; i < 4; i++){ int idx = base + i; v[i] = (idx < n) ? in[idx] : 0; tsum += v[i]; }
  s[tid] = tsum; __syncthreads();
  for (int off = 1; off < 256; off <<= 1){
    int t = (tid >= off) ? s[tid - off] : 0;
    __syncthreads();
    s[tid] += t;
    __syncthreads();
  }
  int excl = s[tid] - tsum;
  #pragma unroll
  for (int i = 0; i < 4; i++){ int idx = base + i; if (idx < n) out[idx] = excl; excl += v[i]; }
  if (tid == 255) bsum[blockIdx.x] = s[255];
}

__global__ __launch_bounds__(256) void k_scan2(const int* __restrict__ bsum, int* __restrict__ boff, int nb){
  __shared__ int s[256];
  int tid = threadIdx.x;
  int v = (tid < nb) ? bsum[tid] : 0;
  s[tid] = v; __syncthreads();
  for (int off = 1; off < 256; off <<= 1){
    int t = (tid >= off) ? s[tid - off] : 0;
    __syncthreads();
    s[tid] += t;
    __syncthreads();
  }
  boff[tid] = s[tid] - v;
}

__global__ __launch_bounds__(256) void k_scan3(int* __restrict__ rs, const int* __restrict__ boff,
                                               int n, int total){
  int i = blockIdx.x * 256 + threadIdx.x;
  if (i < n) rs[i] += boff[i >> 10];
  if (i == 0) rs[n] = total;
}

__global__ __launch_bounds__(256) void k_fill(const int* __restrict__ src, const int* __restrict__ dst,
                                              const int* __restrict__ row_start, int* __restrict__ cursor,
                                              int* __restrict__ csr){
  int e = blockIdx.x * 256 + threadIdx.x;      // grid covers E exactly
  int d = dst[e];
  int pos = atomicAdd(&cursor[d], 1);
  csr[row_start[d] + pos] = src[e];
}

// ---------------- GEMM [rows,128] @ [128,128] + optional (relu -> LN) ----------------
// block = 256 threads, 64 rows/block; fp32 VALU (exact), A staged in LDS.

__global__ __launch_bounds__(256) void k_gemm128(const float* __restrict__ A,
    const float* __restrict__ W, const float* __restrict__ bias,
    const float* __restrict__ gamma, const float* __restrict__ beta,
    float* __restrict__ xout, unsigned short* __restrict__ xbout, int relu_ln)
{
  __shared__ float As[64][132];     // +4 pad: float4-aligned rows, spread banks
  __shared__ float mu_s[64], rs_s[64];
  const int tid = threadIdx.x;
  const long row0 = (long)blockIdx.x * 64;

  const float4* A4 = (const float4*)(A + row0 * HID);
  for (int i = tid; i < 64 * 32; i += 256){
    int r = i >> 5, c = i & 31;
    float4 v = A4[r * 32 + c];
    *(float4*)&As[r][c * 4] = v;
  }
  __syncthreads();

  const int col = tid & 127;
  const int rb  = (tid >> 7) * 32;
  float acc[32];
  {
    float b = bias[col];
    #pragma unroll
    for (int r = 0; r < 32; r++) acc[r] = b;
  }
  for (int k = 0; k < HID; k += 4){
    float w0 = W[(k + 0) * HID + col];
    float w1 = W[(k + 1) * HID + col];
    float w2 = W[(k + 2) * HID + col];
    float w3 = W[(k + 3) * HID + col];
    #pragma unroll
    for (int r = 0; r < 32; r++){
      float4 a = *(const float4*)&As[rb + r][k];
      acc[r] = fmaf(a.w, w3, fmaf(a.z, w2, fmaf(a.y, w1, fmaf(a.x, w0, acc[r]))));
    }
  }

  if (!relu_ln){
    #pragma unroll
    for (int r = 0; r < 32; r++){
      long idx = (row0 + rb + r) * HID + col;
      float v = acc[r];
      xout[idx] = v;
      xbout[idx] = f2bf(v);
    }
  } else {
    __syncthreads();                      // done reading As; reuse for output tile
    #pragma unroll
    for (int r = 0; r < 32; r++)
      As[rb + r][col] = fmaxf(acc[r], 0.f);
    __syncthreads();
    if (tid < 64){
      float s = 0.f, s2 = 0.f;
      for (int k = 0; k < HID; k++){ float v = As[tid][k]; s += v; s2 += v * v; }
      float mu = s * (1.f / HID);
      float var = s2 * (1.f / HID) - mu * mu;
      mu_s[tid] = mu;
      rs_s[tid] = 1.f / sqrtf(var + EPS);
    }
    __syncthreads();
    for (int i = tid; i < 64 * HID; i += 256){
      int r = i >> 7, c = i & 127;
      float v = (As[r][c] - mu_s[r]) * rs_s[r] * gamma[c] + beta[c];
      long idx = (row0 + r) * HID + c;
      xout[idx] = v;
      xbout[idx] = f2bf(v);
    }
  }
}

// ---------------- edge aggregation: h = (sum_{src in N(i)} xb[src] + x[i]) / (deg+1) ----------------
// one wave per node; lane handles 2 columns (one bf16 pair dword per edge)

__global__ __launch_bounds__(256) void k_agg(const int* __restrict__ row_start, const int* __restrict__ csr,
    const u32* __restrict__ xb32, const float* __restrict__ x, float* __restrict__ h)
{
  int gid  = blockIdx.x * 256 + threadIdx.x;   // grid: N/4 blocks -> exactly N waves
  int node = gid >> 6;
  int lane = gid & 63;
  int s0 = row_start[node], s1 = row_start[node + 1];
  float a0 = 0.f, a1 = 0.f;
  int e = s0;
  for (; e + 2 <= s1; e += 2){
    int sa = csr[e], sb = csr[e + 1];
    u32 pa = xb32[(long)sa * 64 + lane];
    u32 pb = xb32[(long)sb * 64 + lane];
    a0 += __uint_as_float(pa << 16);
    a1 += __uint_as_float(pa & 0xffff0000u);
    a0 += __uint_as_float(pb << 16);
    a1 += __uint_as_float(pb & 0xffff0000u);
  }
  if (e < s1){
    int sa = csr[e];
    u32 pa = xb32[(long)sa * 64 + lane];
    a0 += __uint_as_float(pa << 16);
    a1 += __uint_as_float(pa & 0xffff0000u);
  }
  float inv = 1.f / (float)(s1 - s0 + 1);
  long base = (long)node * HID + lane * 2;
  float2 xs = *(const float2*)&x[base];
  float2 r;
  r.x = (a0 + xs.x) * inv;
  r.y = (a1 + xs.y) * inv;
  *(float2*)&h[base] = r;
}

// ---------------- output GEMM [rows,128] @ [128,16] ----------------

__global__ __launch_bounds__(256) void k_gemm_out(const float* __restrict__ x,
    const float* __restrict__ Wo, const float* __restrict__ bo, float* __restrict__ out)
{
  __shared__ float As[16][132];
  __shared__ float Wl[HID * OUTF];
  const int tid = threadIdx.x;
  const long row0 = (long)blockIdx.x * 16;
  const float4* A4 = (const float4*)(x + row0 * HID);
  for (int i = tid; i < 16 * 32; i += 256){
    int r = i >> 5, c = i & 31;
    *(float4*)&As[r][c * 4] = A4[r * 32 + c];
  }
  for (int i = tid; i < HID * OUTF; i += 256) Wl[i] = Wo[i];
  __syncthreads();
  int col = tid & 15, r = tid >> 4;
  float acc = bo[col];
  for (int k = 0; k < HID; k += 4){
    float4 a = *(const float4*)&As[r][k];
    acc = fmaf(a.x, Wl[(k + 0) * OUTF + col],
          fmaf(a.y, Wl[(k + 1) * OUTF + col],
          fmaf(a.z, Wl[(k + 2) * OUTF + col],
          fmaf(a.w, Wl[(k + 3) * OUTF + col], acc))));
  }
  out[(row0 + r) * OUTF + col] = acc;
}

// ---------------- launch ----------------

extern "C" void kernel_launch(void* const* d_in, const int* in_sizes, int n_in,
                              void* d_out, int out_size, void* d_ws, size_t ws_size,
                              hipStream_t stream)
{
  (void)in_sizes; (void)n_in; (void)out_size; (void)ws_size;
  const float* nodes = (const float*)d_in[0];
  const int*   src   = (const int*)d_in[1];
  const int*   dst   = (const int*)d_in[2];
  const float* W_in  = (const float*)d_in[3];
  const float* b_in  = (const float*)d_in[4];
  const float* Ws    = (const float*)d_in[5];
  const float* bs    = (const float*)d_in[6];
  const float* gam   = (const float*)d_in[7];
  const float* bet   = (const float*)d_in[8];
  const float* W_out = (const float*)d_in[9];
  const float* b_out = (const float*)d_in[10];
  float* out = (float*)d_out;

  size_t off = 0;
  auto bump = [&](size_t bytes) -> char* {
    char* p = (char*)d_ws + off;
    off = (off + bytes + 255) & ~(size_t)255;
    return p;
  };
  int* row_start = (int*)bump((N_NODES + 1) * sizeof(int));
  int* cnt       = (int*)bump((size_t)N_NODES * sizeof(int));
  int* bsum      = (int*)bump(256 * sizeof(int));
  int* boff      = (int*)bump(256 * sizeof(int));
  int* csr       = (int*)bump((size_t)N_EDGES * sizeof(int));
  float* x       = (float*)bump((size_t)N_NODES * HID * sizeof(float));
  float* h       = (float*)bump((size_t)N_NODES * HID * sizeof(float));
  unsigned short* xb = (unsigned short*)bump((size_t)N_NODES * HID * sizeof(unsigned short));

  hipMemsetAsync(cnt, 0, (size_t)N_NODES * sizeof(int), stream);
  k_deg<<<N_EDGES / 256, 256, 0, stream>>>(dst, cnt);
  int nb = (N_NODES + 1023) / 1024;   // 196
  k_scan1<<<nb, 256, 0, stream>>>(cnt, row_start, bsum, N_NODES);
  k_scan2<<<1, 256, 0, stream>>>(bsum, boff, nb);
  k_scan3<<<(N_NODES + 255) / 256, 256, 0, stream>>>(row_start, boff, N_NODES, N_EDGES);
  hipMemsetAsync(cnt, 0, (size_t)N_NODES * sizeof(int), stream);
  k_fill<<<N_EDGES / 256, 256, 0, stream>>>(src, dst, row_start, cnt, csr);

  k_gemm128<<<N_NODES / 64, 256, 0, stream>>>(nodes, W_in, b_in, nullptr, nullptr, x, xb, 0);
  for (int l = 0; l < LAYERS; l++){
    k_agg<<<N_NODES / 4, 256, 0, stream>>>(row_start, csr, (const u32*)xb, x, h);
    k_gemm128<<<N_NODES / 64, 256, 0, stream>>>(h, Ws + (size_t)l * HID * HID, bs + l * HID,
                                                gam + l * HID, bet + l * HID, x, xb, 1);
  }
  k_gemm_out<<<N_NODES / 16, 256, 0, stream>>>(x, W_out, b_out, out);
}

// Round 2
// 1901.287 us; speedup vs baseline: 1.3177x; 1.3177x over previous
//
#include <hip/hip_runtime.h>

#define N_NODES 200000
#define N_EDGES 6400000
#define HID 128
#define OUTF 16
#define LAYERS 3
#define EPS 1e-5f

typedef unsigned int u32;

__device__ __forceinline__ unsigned short f2bf(float f){
  unsigned int u = __float_as_uint(f);
  u += 0x7fffu + ((u >> 16) & 1u);   // RNE
  return (unsigned short)(u >> 16);
}
__device__ __forceinline__ u32 pack2bf(float lo, float hi){
  return (u32)f2bf(lo) | ((u32)f2bf(hi) << 16);
}

// ---------------- CSR build ----------------

__global__ __launch_bounds__(256) void k_deg(const int* __restrict__ dst, int* __restrict__ cnt){
  int e = blockIdx.x * 256 + threadIdx.x;      // grid covers E exactly
  atomicAdd(&cnt[dst[e]], 1);
}

__global__ __launch_bounds__(256) void k_scan1(const int* __restrict__ in, int* __restrict__ out,
                                               int* __restrict__ bsum, int n){
  __shared__ int s[256];
  int tid = threadIdx.x;
  int base = blockIdx.x * 1024 + tid * 4;
  int v[4]; int tsum = 0;
  #pragma unroll
  for (int i = 0; i < 4; i++){ int idx = base + i; v[i] = (idx < n) ? in[idx] : 0; tsum += v[i]; }
  s[tid] = tsum; __syncthreads();
  for (int off = 1; off < 256; off <<= 1){
    int t = (tid >= off) ? s[tid - off] : 0;
    __syncthreads();
    s[tid] += t;
    __syncthreads();
  }
  int excl = s[tid] - tsum;
  #pragma unroll
  for (int i = 0; i < 4; i++){ int idx = base + i; if (idx < n) out[idx] = excl; excl += v[i]; }
  if (tid == 255) bsum[blockIdx.x] = s[255];
}

__global__ __launch_bounds__(256) void k_scan2(const int* __restrict__ bsum, int* __restrict__ boff, int nb){
  __shared__ int s[256];
  int tid = threadIdx.x;
  int v = (tid < nb) ? bsum[tid] : 0;
  s[tid] = v; __syncthreads();
  for (int off = 1; off < 256; off <<= 1){
    int t = (tid >= off) ? s[tid - off] : 0;
    __syncthreads();
    s[tid] += t;
    __syncthreads();
  }
  boff[tid] = s[tid] - v;
}

__global__ __launch_bounds__(256) void k_scan3(int* __restrict__ rs, const int* __restrict__ boff,
                                               int n, int total){
  int i = blockIdx.x * 256 + threadIdx.x;
  if (i < n) rs[i] += boff[i >> 10];
  if (i == 0) rs[n] = total;
}

__global__ __launch_bounds__(256) void k_fill(const int* __restrict__ src, const int* __restrict__ dst,
                                              const int* __restrict__ row_start, int* __restrict__ cursor,
                                              int* __restrict__ csr){
  int e = blockIdx.x * 256 + threadIdx.x;      // grid covers E exactly
  int d = dst[e];
  int pos = atomicAdd(&cursor[d], 1);
  csr[row_start[d] + pos] = src[e];
}

// ---------------- GEMM [rows,128] @ [128,128] + optional (relu -> LN) ----------------
// block = 256 threads, tile 64 rows x 128 cols; per-thread 8 rows x 4 cols.
// fp32 VALU (exact). A staged in LDS (float4 reads), W read float4 from L2.

__global__ __launch_bounds__(256) void k_gemm128(const float* __restrict__ A,
    const float* __restrict__ W, const float* __restrict__ bias,
    const float* __restrict__ gamma, const float* __restrict__ beta,
    float* __restrict__ xout, u32* __restrict__ xbout, int relu_ln)
{
  __shared__ float As[64][132];     // +4 pad keeps float4 alignment, spreads banks
  __shared__ float part[64][4][2];
  __shared__ float mu_s[64], rs_s[64];
  __shared__ float gam_s[128], bet_s[128];
  const int tid = threadIdx.x;
  const long row0 = (long)blockIdx.x * 64;

  const float4* A4 = (const float4*)(A + row0 * HID);
  for (int i = tid; i < 64 * 32; i += 256){
    int r = i >> 5, c = i & 31;
    *(float4*)&As[r][c * 4] = A4[r * 32 + c];
  }
  if (relu_ln && tid < 128){ gam_s[tid] = gamma[tid]; bet_s[tid] = beta[tid]; }
  __syncthreads();

  const int cg = tid & 31;        // cols 4cg..4cg+3
  const int rg = tid >> 5;        // rows rg*8..rg*8+7
  const int c0 = cg * 4;
  float acc[8][4];
  {
    float4 b = *(const float4*)&bias[c0];
    #pragma unroll
    for (int r = 0; r < 8; r++){ acc[r][0]=b.x; acc[r][1]=b.y; acc[r][2]=b.z; acc[r][3]=b.w; }
  }

  for (int k = 0; k < HID; k += 4){
    float4 w0 = *(const float4*)&W[(k + 0) * HID + c0];
    float4 w1 = *(const float4*)&W[(k + 1) * HID + c0];
    float4 w2 = *(const float4*)&W[(k + 2) * HID + c0];
    float4 w3 = *(const float4*)&W[(k + 3) * HID + c0];
    #pragma unroll
    for (int r = 0; r < 8; r++){
      float4 a = *(const float4*)&As[rg * 8 + r][k];
      acc[r][0] = fmaf(a.w, w3.x, fmaf(a.z, w2.x, fmaf(a.y, w1.x, fmaf(a.x, w0.x, acc[r][0]))));
      acc[r][1] = fmaf(a.w, w3.y, fmaf(a.z, w2.y, fmaf(a.y, w1.y, fmaf(a.x, w0.y, acc[r][1]))));
      acc[r][2] = fmaf(a.w, w3.z, fmaf(a.z, w2.z, fmaf(a.y, w1.z, fmaf(a.x, w0.z, acc[r][2]))));
      acc[r][3] = fmaf(a.w, w3.w, fmaf(a.z, w2.w, fmaf(a.y, w1.w, fmaf(a.x, w0.w, acc[r][3]))));
    }
  }

  if (!relu_ln){
    #pragma unroll
    for (int r = 0; r < 8; r++){
      long row = row0 + rg * 8 + r;
      float4 v; v.x = acc[r][0]; v.y = acc[r][1]; v.z = acc[r][2]; v.w = acc[r][3];
      *(float4*)&xout[row * HID + c0] = v;
      uint2 p; p.x = pack2bf(v.x, v.y); p.y = pack2bf(v.z, v.w);
      *(uint2*)&xbout[(row * HID + c0) >> 1] = p;
    }
  } else {
    __syncthreads();                      // done reading As; reuse for relu tile
    #pragma unroll
    for (int r = 0; r < 8; r++){
      float4 v;
      v.x = fmaxf(acc[r][0], 0.f); v.y = fmaxf(acc[r][1], 0.f);
      v.z = fmaxf(acc[r][2], 0.f); v.w = fmaxf(acc[r][3], 0.f);
      *(float4*)&As[rg * 8 + r][c0] = v;
    }
    __syncthreads();
    {
      // partial sums: thread -> row = tid>>2, quarter q = tid&3 (2-way conflict = free)
      int row = tid >> 2, q = tid & 3;
      float s = 0.f, s2 = 0.f;
      #pragma unroll 8
      for (int c = 0; c < 32; c++){ float v = As[row][q * 32 + c]; s += v; s2 += v * v; }
      part[row][q][0] = s; part[row][q][1] = s2;
    }
    __syncthreads();
    if (tid < 64){
      float s  = part[tid][0][0] + part[tid][1][0] + part[tid][2][0] + part[tid][3][0];
      float s2 = part[tid][0][1] + part[tid][1][1] + part[tid][2][1] + part[tid][3][1];
      float mu = s * (1.f / HID);
      float var = s2 * (1.f / HID) - mu * mu;
      mu_s[tid] = mu;
      rs_s[tid] = 1.f / sqrtf(var + EPS);
    }
    __syncthreads();
    for (int i = tid; i < 64 * 32; i += 256){
      int r = i >> 5, c4 = (i & 31) * 4;
      float4 v = *(float4*)&As[r][c4];
      float mu = mu_s[r], rs = rs_s[r];
      v.x = (v.x - mu) * rs * gam_s[c4 + 0] + bet_s[c4 + 0];
      v.y = (v.y - mu) * rs * gam_s[c4 + 1] + bet_s[c4 + 1];
      v.z = (v.z - mu) * rs * gam_s[c4 + 2] + bet_s[c4 + 2];
      v.w = (v.w - mu) * rs * gam_s[c4 + 3] + bet_s[c4 + 3];
      long row = row0 + r;
      *(float4*)&xout[row * HID + c4] = v;
      uint2 p; p.x = pack2bf(v.x, v.y); p.y = pack2bf(v.z, v.w);
      *(uint2*)&xbout[(row * HID + c4) >> 1] = p;
    }
  }
}

// ---------------- edge aggregation: h = (sum_{src in N(i)} xb[src] + x[i]) / (deg+1) ----------------
// one wave per node; lane handles 2 columns. Unroll 8 -> 8 independent gathers in flight.

__global__ __launch_bounds__(256) void k_agg(const int* __restrict__ row_start, const int* __restrict__ csr,
    const u32* __restrict__ xb32, const float* __restrict__ x, float* __restrict__ h)
{
  int gid  = blockIdx.x * 256 + threadIdx.x;   // grid: N/4 blocks -> exactly N waves
  int node = gid >> 6;
  int lane = gid & 63;
  int s0 = row_start[node], s1 = row_start[node + 1];
  float a0 = 0.f, a1 = 0.f;
  int e = s0;
  for (; e + 8 <= s1; e += 8){
    int i0 = csr[e + 0], i1 = csr[e + 1], i2 = csr[e + 2], i3 = csr[e + 3];
    int i4 = csr[e + 4], i5 = csr[e + 5], i6 = csr[e + 6], i7 = csr[e + 7];
    u32 p0 = xb32[(long)i0 * 64 + lane];
    u32 p1 = xb32[(long)i1 * 64 + lane];
    u32 p2 = xb32[(long)i2 * 64 + lane];
    u32 p3 = xb32[(long)i3 * 64 + lane];
    u32 p4 = xb32[(long)i4 * 64 + lane];
    u32 p5 = xb32[(long)i5 * 64 + lane];
    u32 p6 = xb32[(long)i6 * 64 + lane];
    u32 p7 = xb32[(long)i7 * 64 + lane];
    a0 += __uint_as_float(p0 << 16) + __uint_as_float(p1 << 16)
        + __uint_as_float(p2 << 16) + __uint_as_float(p3 << 16)
        + __uint_as_float(p4 << 16) + __uint_as_float(p5 << 16)
        + __uint_as_float(p6 << 16) + __uint_as_float(p7 << 16);
    a1 += __uint_as_float(p0 & 0xffff0000u) + __uint_as_float(p1 & 0xffff0000u)
        + __uint_as_float(p2 & 0xffff0000u) + __uint_as_float(p3 & 0xffff0000u)
        + __uint_as_float(p4 & 0xffff0000u) + __uint_as_float(p5 & 0xffff0000u)
        + __uint_as_float(p6 & 0xffff0000u) + __uint_as_float(p7 & 0xffff0000u);
  }
  for (; e < s1; e++){
    int sa = csr[e];
    u32 pa = xb32[(long)sa * 64 + lane];
    a0 += __uint_as_float(pa << 16);
    a1 += __uint_as_float(pa & 0xffff0000u);
  }
  float inv = 1.f / (float)(s1 - s0 + 1);
  long base = (long)node * HID + lane * 2;
  float2 xs = *(const float2*)&x[base];
  float2 r;
  r.x = (a0 + xs.x) * inv;
  r.y = (a1 + xs.y) * inv;
  *(float2*)&h[base] = r;
}

// ---------------- output GEMM [rows,128] @ [128,16] ----------------

__global__ __launch_bounds__(256) void k_gemm_out(const float* __restrict__ x,
    const float* __restrict__ Wo, const float* __restrict__ bo, float* __restrict__ out)
{
  __shared__ float As[16][132];
  __shared__ float Wl[HID * OUTF];
  const int tid = threadIdx.x;
  const long row0 = (long)blockIdx.x * 16;
  const float4* A4 = (const float4*)(x + row0 * HID);
  for (int i = tid; i < 16 * 32; i += 256){
    int r = i >> 5, c = i & 31;
    *(float4*)&As[r][c * 4] = A4[r * 32 + c];
  }
  for (int i = tid; i < HID * OUTF; i += 256) Wl[i] = Wo[i];
  __syncthreads();
  int col = tid & 15, r = tid >> 4;
  float acc = bo[col];
  for (int k = 0; k < HID; k += 4){
    float4 a = *(const float4*)&As[r][k];
    acc = fmaf(a.x, Wl[(k + 0) * OUTF + col],
          fmaf(a.y, Wl[(k + 1) * OUTF + col],
          fmaf(a.z, Wl[(k + 2) * OUTF + col],
          fmaf(a.w, Wl[(k + 3) * OUTF + col], acc))));
  }
  out[(row0 + r) * OUTF + col] = acc;
}

// ---------------- launch ----------------

extern "C" void kernel_launch(void* const* d_in, const int* in_sizes, int n_in,
                              void* d_out, int out_size, void* d_ws, size_t ws_size,
                              hipStream_t stream)
{
  (void)in_sizes; (void)n_in; (void)out_size; (void)ws_size;
  const float* nodes = (const float*)d_in[0];
  const int*   src   = (const int*)d_in[1];
  const int*   dst   = (const int*)d_in[2];
  const float* W_in  = (const float*)d_in[3];
  const float* b_in  = (const float*)d_in[4];
  const float* Ws    = (const float*)d_in[5];
  const float* bs    = (const float*)d_in[6];
  const float* gam   = (const float*)d_in[7];
  const float* bet   = (const float*)d_in[8];
  const float* W_out = (const float*)d_in[9];
  const float* b_out = (const float*)d_in[10];
  float* out = (float*)d_out;

  size_t off = 0;
  auto bump = [&](size_t bytes) -> char* {
    char* p = (char*)d_ws + off;
    off = (off + bytes + 255) & ~(size_t)255;
    return p;
  };
  int* row_start = (int*)bump((N_NODES + 1) * sizeof(int));
  int* cnt       = (int*)bump((size_t)N_NODES * sizeof(int));
  int* bsum      = (int*)bump(256 * sizeof(int));
  int* boff      = (int*)bump(256 * sizeof(int));
  int* csr       = (int*)bump((size_t)N_EDGES * sizeof(int));
  float* x       = (float*)bump((size_t)N_NODES * HID * sizeof(float));
  float* h       = (float*)bump((size_t)N_NODES * HID * sizeof(float));
  u32* xb        = (u32*)bump((size_t)N_NODES * HID * sizeof(unsigned short));

  hipMemsetAsync(cnt, 0, (size_t)N_NODES * sizeof(int), stream);
  k_deg<<<N_EDGES / 256, 256, 0, stream>>>(dst, cnt);
  int nb = (N_NODES + 1023) / 1024;   // 196
  k_scan1<<<nb, 256, 0, stream>>>(cnt, row_start, bsum, N_NODES);
  k_scan2<<<1, 256, 0, stream>>>(bsum, boff, nb);
  k_scan3<<<(N_NODES + 255) / 256, 256, 0, stream>>>(row_start, boff, N_NODES, N_EDGES);
  hipMemsetAsync(cnt, 0, (size_t)N_NODES * sizeof(int), stream);
  k_fill<<<N_EDGES / 256, 256, 0, stream>>>(src, dst, row_start, cnt, csr);

  k_gemm128<<<N_NODES / 64, 256, 0, stream>>>(nodes, W_in, b_in, nullptr, nullptr, x, xb, 0);
  for (int l = 0; l < LAYERS; l++){
    k_agg<<<N_NODES / 4, 256, 0, stream>>>(row_start, csr, xb, x, h);
    k_gemm128<<<N_NODES / 64, 256, 0, stream>>>(h, Ws + (size_t)l * HID * HID, bs + l * HID,
                                                gam + l * HID, bet + l * HID, x, xb, 1);
  }
  k_gemm_out<<<N_NODES / 16, 256, 0, stream>>>(x, W_out, b_out, out);
}